// Round 1
// baseline (476.452 us; speedup 1.0000x reference)
//
#include <hip/hip_runtime.h>
#include <hip/hip_bf16.h>

// Problem constants
#define BD   16
#define LQ   512
#define LK   4096
#define DM   128

typedef __attribute__((ext_vector_type(8))) short  short8;
typedef __attribute__((ext_vector_type(4))) float  f32x4;
typedef __attribute__((ext_vector_type(4))) int    i32x4;
typedef __attribute__((ext_vector_type(4))) unsigned short u16x4;

// ws layout in units of unsigned short (bf16 elements)
#define WQT_HI_S 0
#define WQT_LO_S 16384
#define WKT_HI_S 32768
#define WKT_LO_S 49152
#define QHI_S    65536
#define QLO_S    1114112
#define KHI_S    2162688
#define KLO_S    10551296
// total shorts = 18,939,904 -> 37,879,808 bytes of d_ws used

static __device__ __forceinline__ unsigned short bf16_rne(float x) {
    union { float f; unsigned int u; } v; v.f = x;
    unsigned int u = v.u;
    u += 0x7FFFu + ((u >> 16) & 1u);   // round-to-nearest-even
    return (unsigned short)(u >> 16);
}
static __device__ __forceinline__ float bf16_f32(unsigned short h) {
    union { unsigned int u; float f; } v; v.u = ((unsigned int)h) << 16;
    return v.f;
}

// ---------------- kernel 1: transpose + hi/lo split of Wq, Wk ----------------
__global__ void setup_wt(const float* __restrict__ Wq, const float* __restrict__ Wk,
                         unsigned short* __restrict__ ws) {
    const float* W = (blockIdx.x == 0) ? Wq : Wk;
    unsigned short* hi = ws + ((blockIdx.x == 0) ? WQT_HI_S : WKT_HI_S);
    unsigned short* lo = ws + ((blockIdx.x == 0) ? WQT_LO_S : WKT_LO_S);
    int tid = threadIdx.x;
    #pragma unroll
    for (int i = 0; i < 64; ++i) {
        int idx = i * 256 + tid;          // 128*128 = 16384 elements
        int d = idx >> 7, e = idx & 127;
        float x = W[idx];                 // W[d][e]
        unsigned short h = bf16_rne(x);
        unsigned short l = bf16_rne(x - bf16_f32(h));
        hi[e * 128 + d] = h;              // WT[e][d]
        lo[e * 128 + d] = l;
    }
}

// ---------------- kernel 2: projections q = query@Wq+bq, k = key@Wk+bk ------
// Swapped-operand MFMA: A = WT tile (rows = out-col e), B = source rows.
// C layout: lane col (l&15) = src row, lane rows 4g+r = 4 consecutive e.
__global__ __launch_bounds__(256) void proj_kernel(
        const float* __restrict__ query, const float* __restrict__ key,
        const float* __restrict__ bq, const float* __restrict__ bk,
        unsigned short* __restrict__ ws) {
    const int wave = threadIdx.x >> 6, lane = threadIdx.x & 63;
    const int r = lane & 15, g = lane >> 4;
    int rowtile = blockIdx.x * 4 + wave;   // 4608 tiles: 512 q + 4096 k

    const float* src; const float* bias;
    const unsigned short *wthi, *wtlo;
    unsigned short *ohi, *olo;
    int rowbase;
    if (rowtile < 512) {
        src = query; bias = bq;
        wthi = ws + WQT_HI_S; wtlo = ws + WQT_LO_S;
        ohi = ws + QHI_S; olo = ws + QLO_S;
        rowbase = rowtile * 16;
    } else {
        int kt = rowtile - 512;
        src = key; bias = bk;
        wthi = ws + WKT_HI_S; wtlo = ws + WKT_LO_S;
        ohi = ws + KHI_S; olo = ws + KLO_S;
        rowbase = kt * 16;
    }

    f32x4 acc[8];
    #pragma unroll
    for (int t = 0; t < 8; ++t) acc[t] = (f32x4){0.f, 0.f, 0.f, 0.f};

    const float* srow = src + (size_t)(rowbase + r) * DM + g * 8;
    #pragma unroll
    for (int s = 0; s < 4; ++s) {
        const f32x4* p = (const f32x4*)(srow + s * 32);
        f32x4 x0 = p[0];
        f32x4 x1 = p[1];
        short8 bh, bl;
        #pragma unroll
        for (int j = 0; j < 8; ++j) {
            float x = (j < 4) ? x0[j] : x1[j - 4];
            unsigned short h = bf16_rne(x);
            bh[j] = (short)h;
            bl[j] = (short)bf16_rne(x - bf16_f32(h));
        }
        #pragma unroll
        for (int t = 0; t < 8; ++t) {
            short8 ah = *(const short8*)(wthi + (t * 16 + r) * DM + s * 32 + g * 8);
            short8 al = *(const short8*)(wtlo + (t * 16 + r) * DM + s * 32 + g * 8);
            acc[t] = __builtin_amdgcn_mfma_f32_16x16x32_bf16(ah, bh, acc[t], 0, 0, 0);
            acc[t] = __builtin_amdgcn_mfma_f32_16x16x32_bf16(ah, bl, acc[t], 0, 0, 0);
            acc[t] = __builtin_amdgcn_mfma_f32_16x16x32_bf16(al, bh, acc[t], 0, 0, 0);
        }
    }

    #pragma unroll
    for (int t = 0; t < 8; ++t) {
        f32x4 bv = *(const f32x4*)(bias + t * 16 + g * 4);
        u16x4 hs, ls;
        #pragma unroll
        for (int rr = 0; rr < 4; ++rr) {
            float v = acc[t][rr] + bv[rr];
            unsigned short h = bf16_rne(v);
            hs[rr] = h;
            ls[rr] = bf16_rne(v - bf16_f32(h));
        }
        size_t o = (size_t)(rowbase + r) * DM + t * 16 + g * 4;
        *(u16x4*)(ohi + o) = hs;
        *(u16x4*)(olo + o) = ls;
    }
}

// ---------------- kernel 3: scores + tanh clip + mask + softmax -------------
// Per wg: (batch, 16 q-rows). 8 waves, wave w owns k-cols [w*512, w*512+512).
// Swapped QK^T: C[i][j]: i = k-col (lane rows, 4 consecutive), j = q-row (l&15).
__global__ __launch_bounds__(512, 2) void attn_kernel(
        const int* __restrict__ mask, float* __restrict__ out,
        const unsigned short* __restrict__ ws) {
    int wg = blockIdx.x;                       // 512
    int swz = (wg & 7) * 64 + (wg >> 3);       // bijective XCD swizzle (512 % 8 == 0)
    int b = swz >> 5, qt = swz & 31;
    const int wave = threadIdx.x >> 6, lane = threadIdx.x & 63;
    const int r = lane & 15, g = lane >> 4;

    const unsigned short* qhi = ws + QHI_S;
    const unsigned short* qlo = ws + QLO_S;
    const unsigned short* khi = ws + KHI_S;
    const unsigned short* klo = ws + KLO_S;

    const int qrow_g = b * LQ + qt * 16 + r;   // global q row for this lane (as B col)

    // q fragments (B operand), 4 K-steps, hi+lo
    short8 qh[4], ql[4];
    #pragma unroll
    for (int s = 0; s < 4; ++s) {
        qh[s] = *(const short8*)(qhi + (size_t)qrow_g * DM + s * 32 + g * 8);
        ql[s] = *(const short8*)(qlo + (size_t)qrow_g * DM + s * 32 + g * 8);
    }

    f32x4 acc[32];
    #pragma unroll
    for (int t = 0; t < 32; ++t) acc[t] = (f32x4){0.f, 0.f, 0.f, 0.f};

    const unsigned short* khrow = khi + (size_t)(b * LK + wave * 512 + r) * DM + g * 8;
    const unsigned short* klrow = klo + (size_t)(b * LK + wave * 512 + r) * DM + g * 8;

    #pragma unroll
    for (int t = 0; t < 32; ++t) {
        const int off = t * 16 * DM;           // 16 k-rows per tile
        #pragma unroll
        for (int s = 0; s < 4; ++s) {
            short8 ah = *(const short8*)(khrow + off + s * 32);
            short8 al = *(const short8*)(klrow + off + s * 32);
            acc[t] = __builtin_amdgcn_mfma_f32_16x16x32_bf16(ah, qh[s], acc[t], 0, 0, 0);
            acc[t] = __builtin_amdgcn_mfma_f32_16x16x32_bf16(ah, ql[s], acc[t], 0, 0, 0);
            acc[t] = __builtin_amdgcn_mfma_f32_16x16x32_bf16(al, qh[s], acc[t], 0, 0, 0);
        }
    }

    // tanh clip + scale, track per-lane max (lane holds one q-row only)
    const float C1 = 0.8838834764831844f;      // 10 / sqrt(128)
    float m = -1e30f;
    #pragma unroll
    for (int t = 0; t < 32; ++t) {
        #pragma unroll
        for (int rr = 0; rr < 4; ++rr) {
            float x = acc[t][rr];
            float ax = fabsf(x);
            float e = __expf(ax * 2.0f);                      // e^{2|x|}, inf-safe
            float th = 1.0f - 2.0f * __builtin_amdgcn_rcpf(e + 1.0f);
            float sp = C1 * copysignf(th, x);
            acc[t][rr] = sp;
            m = fmaxf(m, sp);
        }
    }
    m = fmaxf(m, __shfl_xor(m, 16, 64));
    m = fmaxf(m, __shfl_xor(m, 32, 64));

    __shared__ float redmax[8 * 16];
    __shared__ float redsum[8 * 16];
    if (lane < 16) redmax[wave * 16 + lane] = m;
    __syncthreads();
    float M = redmax[r];
    #pragma unroll
    for (int w = 1; w < 8; ++w) M = fmaxf(M, redmax[w * 16 + r]);

    // exp + mask + per-row sum
    float psum = 0.f;
    const int* mrow = mask + (size_t)(b * LQ + qt * 16 + r) * LK + wave * 512 + g * 4;
    #pragma unroll
    for (int t = 0; t < 32; ++t) {
        i32x4 mv = __builtin_nontemporal_load((const i32x4*)(mrow + t * 16));
        #pragma unroll
        for (int rr = 0; rr < 4; ++rr) {
            float p = __expf(acc[t][rr] - M);
            p = (mv[rr] != 0) ? p : 0.0f;
            acc[t][rr] = p;
            psum += p;
        }
    }
    psum += __shfl_xor(psum, 16, 64);
    psum += __shfl_xor(psum, 32, 64);
    if (lane < 16) redsum[wave * 16 + lane] = psum;
    __syncthreads();
    float S = 0.f;
    #pragma unroll
    for (int w = 0; w < 8; ++w) S += redsum[w * 16 + r];
    float rinv = 1.0f / S;

    float* orow = out + (size_t)(b * LQ + qt * 16 + r) * LK + wave * 512 + g * 4;
    #pragma unroll
    for (int t = 0; t < 32; ++t) {
        f32x4 o;
        #pragma unroll
        for (int rr = 0; rr < 4; ++rr) o[rr] = acc[t][rr] * rinv;
        __builtin_nontemporal_store(o, (f32x4*)(orow + t * 16));
    }
}

extern "C" void kernel_launch(void* const* d_in, const int* in_sizes, int n_in,
                              void* d_out, int out_size, void* d_ws, size_t ws_size,
                              hipStream_t stream) {
    const float* query = (const float*)d_in[0];
    const float* key   = (const float*)d_in[1];
    const int*   mask  = (const int*)d_in[2];
    const float* Wq    = (const float*)d_in[3];
    const float* bq    = (const float*)d_in[4];
    const float* Wk    = (const float*)d_in[5];
    const float* bk    = (const float*)d_in[6];
    float* out = (float*)d_out;
    unsigned short* ws = (unsigned short*)d_ws;

    setup_wt<<<2, 256, 0, stream>>>(Wq, Wk, ws);
    proj_kernel<<<(512 + 4096) / 4, 256, 0, stream>>>(query, key, bq, bk, ws);
    attn_kernel<<<BD * (LQ / 16), 512, 0, stream>>>(mask, out, ws);
}